// Round 9
// baseline (525.642 us; speedup 1.0000x reference)
//
#include <hip/hip_runtime.h>
#include <stdint.h>

// ResBlock: GraphConv(64->128) -> BN -> ReLU -> GraphConv(128->128) -> BN
//           + (x @ Wlin^T + blin) residual -> ReLU.
// Runtime dtype probe (bf16 vs f32).
// R8->R9: dense MFMA kernels are latency-bound (MfmaUtil 3%, VALU 11%, HBM 9%,
// occupancy 17%). Changes: (1) 32-row blocks (half LDS -> 2x blocks, higher
// occupancy ceiling, shorter barrier scope); (2) shfl_xor-packed u32 stores
// (half the store instructions). Binning/aggregation/BN unchanged from R8.

#define CIN 64
#define COUT 128
#define BN_EPS 1e-5f
#define CURPAD 16
#define PSH 10                 // partition = dst >> PSH  (1024 nodes)
#define PNODES (1 << PSH)
#define MAXP 128               // supports N <= 131072

typedef unsigned short u16;
typedef short short8 __attribute__((ext_vector_type(8)));
typedef float f32x4 __attribute__((ext_vector_type(4)));

__device__ __forceinline__ float bf2f(u16 u) {
    union { unsigned int i; float f; } v; v.i = ((unsigned int)u) << 16; return v.f;
}
__device__ __forceinline__ u16 f2bf(float f) {
    union { float f; unsigned int i; } v; v.f = f;
    unsigned int r = v.i + 0x7fffu + ((v.i >> 16) & 1u);  // RNE; finite inputs
    return (u16)(r >> 16);
}
__device__ __forceinline__ float lo16(unsigned int w) { return bf2f((u16)(w & 0xffffu)); }
__device__ __forceinline__ float hi16(unsigned int w) { return bf2f((u16)(w >> 16)); }

template<bool BF> __device__ __forceinline__ float ldf(const void* p, long i) {
    if (BF) return bf2f(((const u16*)p)[i]);
    return ((const float*)p)[i];
}
template<bool BF> __device__ __forceinline__ short8 ld8(const void* p, long i) {
    if (BF) return *(const short8*)((const u16*)p + i);
    const float* f = (const float*)p + i;
    short8 r;
#pragma unroll
    for (int j = 0; j < 8; ++j) r[j] = (short)f2bf(f[j]);
    return r;
}

// ---- coalesced ROWS-row chunk staging into padded LDS (bf16 in LDS) ------
template<bool BF, int RL, int ROWS>
__device__ __forceinline__ void stage_tile(const void* g, long first_row,
                                           u16* lds, int stride, int col_off,
                                           int n, int tid) {
    if (BF) {
        const int SPR = RL / 8;
        const int NPT = ROWS * SPR / 256;
#pragma unroll
        for (int i = 0; i < NPT; ++i) {
            int s = tid + i * 256;
            int row = s / SPR, within = s % SPR;
            long rg = first_row + row; if (rg > n - 1) rg = n - 1;
            short8 v = *(const short8*)((const u16*)g + rg * RL + within * 8);
            *(short8*)(lds + row * stride + col_off + within * 8) = v;
        }
    } else {
        const int SPR = RL / 4;
        const int NPT = ROWS * SPR / 256;
#pragma unroll
        for (int i = 0; i < NPT; ++i) {
            int s = tid + i * 256;
            int row = s / SPR, within = s % SPR;
            long rg = first_row + row; if (rg > n - 1) rg = n - 1;
            float4 v = *(const float4*)((const float*)g + rg * RL + within * 4);
            u16* d = lds + row * stride + col_off + within * 4;
            d[0] = f2bf(v.x); d[1] = f2bf(v.y); d[2] = f2bf(v.z); d[3] = f2bf(v.w);
        }
    }
}

// stage y0 (bf16, 32 rows) with fused BN0-apply + ReLU
__device__ __forceinline__ void stage_y0p(const u16* y0, long first_row,
                                          u16* lds, int stride,
                                          const float* __restrict__ sc,
                                          const float* __restrict__ sh,
                                          int n, int tid) {
#pragma unroll
    for (int i = 0; i < 2; ++i) {
        int s = tid + i * 256;
        int row = s >> 4, within = s & 15;
        long rg = first_row + row; if (rg > n - 1) rg = n - 1;
        short8 v = *(const short8*)(y0 + rg * COUT + within * 8);
        int c = within * 8;
        short8 o;
#pragma unroll
        for (int j = 0; j < 8; ++j)
            o[j] = (short)f2bf(fmaxf(bf2f((u16)v[j]) * sc[c + j] + sh[c + j], 0.f));
        *(short8*)(lds + row * stride + within * 8) = o;
    }
}

// ---------------- dtype detection ----------------
__global__ void k_detect(const unsigned int* __restrict__ x, int* __restrict__ flag) {
    int lane = threadIdx.x;  // 64
    int cnt = 0;
#pragma unroll
    for (int i = 0; i < 8; ++i) {
        unsigned int w = x[lane * 8 + i];
        unsigned int e0 = (w >> 7) & 0xFFu, e1 = (w >> 23) & 0xFFu;
        cnt += (e0 >= 0x60u && e0 <= 0x8Eu);
        cnt += (e1 >= 0x60u && e1 <= 0x8Eu);
    }
    for (int o = 32; o; o >>= 1) cnt += __shfl_down(cnt, o);
    if (lane == 0) *flag = (cnt > 850) ? 1 : 0;   // 1 => bf16
}

// ---------------- partition build (partition = dst >> PSH) ----------------
__global__ __launch_bounds__(256) void k_phist(const int* __restrict__ dst,
                                               int* __restrict__ pcount, int E, int np) {
    __shared__ int h[MAXP];
    for (int i = threadIdx.x; i < np; i += 256) h[i] = 0;
    __syncthreads();
    int stride = gridDim.x * 256;
    for (int e = blockIdx.x * 256 + threadIdx.x; e < E; e += stride)
        atomicAdd(&h[dst[e] >> PSH], 1);
    __syncthreads();
    for (int i = threadIdx.x; i < np; i += 256)
        if (h[i]) atomicAdd(&pcount[i], h[i]);
}

__global__ void k_pscan(const int* __restrict__ pcount, int* __restrict__ pstart,
                        int* __restrict__ pcursor, int np, int E) {
    __shared__ int s[MAXP];
    int t = threadIdx.x;  // 128 threads
    int v = (t < np) ? pcount[t] : 0;
    s[t] = v; __syncthreads();
    for (int o = 1; o < MAXP; o <<= 1) {
        int u = (t >= o) ? s[t - o] : 0;
        __syncthreads(); s[t] += u; __syncthreads();
    }
    if (t < np) {
        int ex = s[t] - v;
        pstart[t] = ex;
        pcursor[t * CURPAD] = ex;
    }
    if (t == 0) pstart[np] = E;
}

// One 4096-edge tile per block. Per-(block,partition) contiguous runs ->
// each barr cache line written by ~one block (no cross-block false sharing).
// rec = (dst & (PNODES-1)) << 20 | src   (src < 2^20)
__global__ __launch_bounds__(256) void k_pfill(const int* __restrict__ src,
        const int* __restrict__ dst, int* __restrict__ pcursor,
        unsigned int* __restrict__ barr, int E, int np) {
    __shared__ int cnt[MAXP], gb[MAXP], loc[MAXP];
    int tid = threadIdx.x;
    int base = blockIdx.x * 4096;
    for (int i = tid; i < np; i += 256) { cnt[i] = 0; loc[i] = 0; }
    __syncthreads();
    int pk[16]; unsigned int rec[16];
#pragma unroll
    for (int k = 0; k < 16; ++k) {
        int e = base + k * 256 + tid;
        if (e < E) {
            int d = dst[e];
            pk[k] = d >> PSH;
            rec[k] = ((unsigned int)(d & (PNODES - 1)) << 20) | (unsigned int)src[e];
            atomicAdd(&cnt[pk[k]], 1);
        } else pk[k] = -1;
    }
    __syncthreads();
    for (int i = tid; i < np; i += 256)
        if (cnt[i]) gb[i] = atomicAdd(&pcursor[i * CURPAD], cnt[i]);
    __syncthreads();
#pragma unroll
    for (int k = 0; k < 16; ++k) {
        if (pk[k] >= 0) {
            int off = atomicAdd(&loc[pk[k]], 1);
            barr[gb[pk[k]] + off] = rec[k];
        }
    }
}

// Block per partition: LDS counting sort -> node-sorted csr + row_start.
__global__ __launch_bounds__(256) void k_psort(const unsigned int* __restrict__ barr,
        const int* __restrict__ pstart, int* __restrict__ csr,
        int* __restrict__ row_start, int n, int np, int E) {
    __shared__ int hist[PNODES], curs[PNODES], tsum[256];
    int tid = threadIdx.x;
    int p = blockIdx.x;
    int e0 = pstart[p], e1 = pstart[p + 1];
    int node0 = p << PSH;
#pragma unroll
    for (int j = 0; j < PNODES / 256; ++j) hist[tid + j * 256] = 0;
    __syncthreads();
    for (int t = e0 + tid; t < e1; t += 256)
        atomicAdd(&hist[barr[t] >> 20], 1);
    __syncthreads();
    int s0 = hist[tid * 4], s1 = hist[tid * 4 + 1], s2 = hist[tid * 4 + 2], s3 = hist[tid * 4 + 3];
    int sum4 = s0 + s1 + s2 + s3;
    tsum[tid] = sum4; __syncthreads();
    for (int o = 1; o < 256; o <<= 1) {
        int u = (tid >= o) ? tsum[tid - o] : 0;
        __syncthreads(); tsum[tid] += u; __syncthreads();
    }
    int bexc = tsum[tid] - sum4;
    int off0 = bexc, off1 = bexc + s0, off2 = off1 + s1, off3 = off2 + s2;
    curs[tid * 4] = off0; curs[tid * 4 + 1] = off1;
    curs[tid * 4 + 2] = off2; curs[tid * 4 + 3] = off3;
    int nd = node0 + tid * 4;
    if (nd < n)     row_start[nd]     = e0 + off0;
    if (nd + 1 < n) row_start[nd + 1] = e0 + off1;
    if (nd + 2 < n) row_start[nd + 2] = e0 + off2;
    if (nd + 3 < n) row_start[nd + 3] = e0 + off3;
    if (p == np - 1 && tid == 0) row_start[n] = E;
    __syncthreads();
    for (int t = e0 + tid; t < e1; t += 256) {
        unsigned int rec = barr[t];
        int pos = atomicAdd(&curs[rec >> 20], 1);
        csr[e0 + pos] = (int)(rec & 0xFFFFF);
    }
}

// ---------------- aggregation (pull, wave per node, coalesced rows) -------
template<bool BF>
__device__ __forceinline__ void agg0_impl(const void* x, const int* rs, const int* csr,
                                          u16* agg, int n) {
    int i = blockIdx.x * 4 + (threadIdx.x >> 6);
    if (i >= n) return;
    int lane = threadIdx.x & 63;
    int h = lane >> 5, cp = lane & 31;
    int b = rs[i], e = rs[i + 1];
    float a0 = 0.f, a1 = 0.f, b0 = 0.f, b1 = 0.f;
    int t = b + h;
    for (; t + 2 < e; t += 4) {
        int j0 = csr[t], j1 = csr[t + 2];
        if (BF) {
            unsigned int w0 = ((const unsigned int*)x)[(long)j0 * 32 + cp];
            unsigned int w1 = ((const unsigned int*)x)[(long)j1 * 32 + cp];
            a0 += lo16(w0); a1 += hi16(w0);
            b0 += lo16(w1); b1 += hi16(w1);
        } else {
            float2 w0 = ((const float2*)x)[(long)j0 * 32 + cp];
            float2 w1 = ((const float2*)x)[(long)j1 * 32 + cp];
            a0 += w0.x; a1 += w0.y;
            b0 += w1.x; b1 += w1.y;
        }
    }
    for (; t < e; t += 2) {
        int j0 = csr[t];
        if (BF) {
            unsigned int w0 = ((const unsigned int*)x)[(long)j0 * 32 + cp];
            a0 += lo16(w0); a1 += hi16(w0);
        } else {
            float2 w0 = ((const float2*)x)[(long)j0 * 32 + cp];
            a0 += w0.x; a1 += w0.y;
        }
    }
    a0 += b0; a1 += b1;
    a0 += __shfl_xor(a0, 32);
    a1 += __shfl_xor(a1, 32);
    if (h == 0) {
        unsigned int o = (unsigned int)f2bf(a0) | ((unsigned int)f2bf(a1) << 16);
        ((unsigned int*)agg)[(long)i * 32 + cp] = o;
    }
}

__global__ __launch_bounds__(256) void k_agg0(const int* __restrict__ flag,
        const void* x, const int* __restrict__ rs, const int* __restrict__ csr,
        u16* __restrict__ agg, int n) {
    if (*flag) agg0_impl<true >(x, rs, csr, agg, n);
    else       agg0_impl<false>(x, rs, csr, agg, n);
}

// agg1: gathers relu(bn0(y0_raw)); scale/shift applied on the fly. bf16 internal.
__global__ __launch_bounds__(256) void k_agg1(const u16* __restrict__ y0,
        const int* __restrict__ rs, const int* __restrict__ csr,
        const float* __restrict__ scale, const float* __restrict__ shift,
        u16* __restrict__ agg, int n) {
    int i = blockIdx.x * 4 + (threadIdx.x >> 6);
    if (i >= n) return;
    int lane = threadIdx.x & 63;
    int c0 = 2 * lane;
    float s0 = scale[c0], s1 = scale[c0 + 1];
    float h0 = shift[c0], h1 = shift[c0 + 1];
    const unsigned int* y32 = (const unsigned int*)y0;
    int b = rs[i], e = rs[i + 1];
    float a0 = 0.f, a1 = 0.f, b0 = 0.f, b1 = 0.f;
    float c0a = 0.f, c1a = 0.f, d0 = 0.f, d1 = 0.f;
    int t = b;
    for (; t + 4 <= e; t += 4) {
        int j0 = csr[t], j1 = csr[t + 1], j2 = csr[t + 2], j3 = csr[t + 3];
        unsigned int w0 = y32[(long)j0 * 64 + lane];
        unsigned int w1 = y32[(long)j1 * 64 + lane];
        unsigned int w2 = y32[(long)j2 * 64 + lane];
        unsigned int w3 = y32[(long)j3 * 64 + lane];
        a0  += fmaxf(lo16(w0) * s0 + h0, 0.f); a1  += fmaxf(hi16(w0) * s1 + h1, 0.f);
        b0  += fmaxf(lo16(w1) * s0 + h0, 0.f); b1  += fmaxf(hi16(w1) * s1 + h1, 0.f);
        c0a += fmaxf(lo16(w2) * s0 + h0, 0.f); c1a += fmaxf(hi16(w2) * s1 + h1, 0.f);
        d0  += fmaxf(lo16(w3) * s0 + h0, 0.f); d1  += fmaxf(hi16(w3) * s1 + h1, 0.f);
    }
    for (; t < e; ++t) {
        unsigned int w0 = y32[(long)csr[t] * 64 + lane];
        a0 += fmaxf(lo16(w0) * s0 + h0, 0.f); a1 += fmaxf(hi16(w0) * s1 + h1, 0.f);
    }
    float s0t = (a0 + b0) + (c0a + d0);
    float s1t = (a1 + b1) + (c1a + d1);
    ((unsigned int*)agg)[(long)i * 64 + lane] =
        (unsigned int)f2bf(s0t) | ((unsigned int)f2bf(s1t) << 16);
}

// ---- packed u32 store of one accumulator element pair (cols c, c^1) ------
// D layout: col=lane&15 -> lane pair (lr, lr+1) holds adjacent cols.
__device__ __forceinline__ void pack_store(u16* dst, long row, int c, float v, int n,
                                           int lane) {
    float nb = __shfl_xor(v, 1);
    if (((lane & 1) == 0) && row < n) {
        unsigned int pk = (unsigned int)f2bf(v) | ((unsigned int)f2bf(nb) << 16);
        *(unsigned int*)(dst + row * COUT + c) = pk;
    }
}

// ---------------- GEMM0: y0 = [x|agg0] @ [Wr0;Wn0]^T, fused stats ----------
// 32-row blocks, 4 waves x 2 col-tiles.
template<bool BF>
__device__ __forceinline__ void gemm0_impl(const void* x, const u16* agg,
                                           const void* Wr, const void* Wn,
                                           u16* y0, float* sum, float* sumsq,
                                           int n, u16* lds) {
    const int ST = 130;
    int tid = threadIdx.x;
    int wave = tid >> 6, lane = tid & 63, lr = lane & 15, q = lane >> 4;
    long chunk0 = (long)blockIdx.x * 32;

    short8 wf[2][4];
#pragma unroll
    for (int i = 0; i < 2; ++i) {
        int c = (2 * wave + i) * 16 + lr;
#pragma unroll
        for (int ks = 0; ks < 4; ++ks) {
            const void* W = (ks < 2) ? Wr : Wn;
            wf[i][ks] = ld8<BF>(W, (long)c * CIN + (ks & 1) * 32 + q * 8);
        }
    }
    stage_tile<BF, 64, 32>(x, chunk0, lds, ST, 0, n, tid);
    stage_tile<true, 64, 32>(agg, chunk0, lds, ST, 64, n, tid);
    __syncthreads();

    float st[2] = {0.f, 0.f}, sq[2] = {0.f, 0.f};
#pragma unroll
    for (int t = 0; t < 2; ++t) {
        short8 a[4];
#pragma unroll
        for (int ks = 0; ks < 4; ++ks)
            a[ks] = *(const short8*)(lds + (t * 16 + lr) * ST + ks * 32 + q * 8);
#pragma unroll
        for (int i = 0; i < 2; ++i) {
            f32x4 acc = {0.f, 0.f, 0.f, 0.f};
#pragma unroll
            for (int ks = 0; ks < 4; ++ks)
                acc = __builtin_amdgcn_mfma_f32_16x16x32_bf16(a[ks], wf[i][ks], acc, 0, 0, 0);
            int c = (2 * wave + i) * 16 + lr;
#pragma unroll
            for (int r = 0; r < 4; ++r) {
                long row = chunk0 + t * 16 + q * 4 + r;
                if (row < n) { st[i] += acc[r]; sq[i] += acc[r] * acc[r]; }
                pack_store(y0, row, c & ~1, acc[r], n, lane);  // b0 cancels in BN
            }
        }
    }
#pragma unroll
    for (int i = 0; i < 2; ++i) {
        st[i] += __shfl_xor(st[i], 16); st[i] += __shfl_xor(st[i], 32);
        sq[i] += __shfl_xor(sq[i], 16); sq[i] += __shfl_xor(sq[i], 32);
    }
    if (q == 0) {
#pragma unroll
        for (int i = 0; i < 2; ++i) {
            int c = (2 * wave + i) * 16 + lr;
            atomicAdd(&sum[c], st[i]);
            atomicAdd(&sumsq[c], sq[i]);
        }
    }
}

__global__ __launch_bounds__(256) void k_gemm0(const int* __restrict__ flag,
        const void* x, const u16* __restrict__ agg, const void* Wr, const void* Wn,
        u16* __restrict__ y0, float* __restrict__ sum, float* __restrict__ sumsq, int n) {
    __shared__ u16 lds[32 * 130];
    if (*flag) gemm0_impl<true >(x, agg, Wr, Wn, y0, sum, sumsq, n, lds);
    else       gemm0_impl<false>(x, agg, Wr, Wn, y0, sum, sumsq, n, lds);
}

// ---------------- GEMM1: y1 = [relu(bn0(y0))|agg1] @ [Wr1;Wn1]^T, stats ----
template<bool BF>
__device__ __forceinline__ void gemm1_impl(const u16* y0, const u16* agg,
                                           const void* Wr, const void* Wn,
                                           const float* sc0, const float* sh0,
                                           u16* y1, float* sum, float* sumsq,
                                           int n, u16* lds) {
    const int ST = 258;
    int tid = threadIdx.x;
    int wave = tid >> 6, lane = tid & 63, lr = lane & 15, q = lane >> 4;
    long chunk0 = (long)blockIdx.x * 32;

    short8 wf[2][8];
#pragma unroll
    for (int i = 0; i < 2; ++i) {
        int c = (2 * wave + i) * 16 + lr;
#pragma unroll
        for (int ks = 0; ks < 8; ++ks) {
            const void* W = (ks < 4) ? Wr : Wn;
            wf[i][ks] = ld8<BF>(W, (long)c * COUT + (ks & 3) * 32 + q * 8);
        }
    }
    stage_y0p(y0, chunk0, lds, ST, sc0, sh0, n, tid);
    stage_tile<true, 128, 32>(agg, chunk0, lds, ST, 128, n, tid);
    __syncthreads();

    float st[2] = {0.f, 0.f}, sq[2] = {0.f, 0.f};
#pragma unroll
    for (int t = 0; t < 2; ++t) {
        short8 a[8];
#pragma unroll
        for (int ks = 0; ks < 8; ++ks)
            a[ks] = *(const short8*)(lds + (t * 16 + lr) * ST + ks * 32 + q * 8);
#pragma unroll
        for (int i = 0; i < 2; ++i) {
            f32x4 acc = {0.f, 0.f, 0.f, 0.f};
#pragma unroll
            for (int ks = 0; ks < 8; ++ks)
                acc = __builtin_amdgcn_mfma_f32_16x16x32_bf16(a[ks], wf[i][ks], acc, 0, 0, 0);
            int c = (2 * wave + i) * 16 + lr;
#pragma unroll
            for (int r = 0; r < 4; ++r) {
                long row = chunk0 + t * 16 + q * 4 + r;
                if (row < n) { st[i] += acc[r]; sq[i] += acc[r] * acc[r]; }
                pack_store(y1, row, c & ~1, acc[r], n, lane);  // b1 cancels in BN
            }
        }
    }
#pragma unroll
    for (int i = 0; i < 2; ++i) {
        st[i] += __shfl_xor(st[i], 16); st[i] += __shfl_xor(st[i], 32);
        sq[i] += __shfl_xor(sq[i], 16); sq[i] += __shfl_xor(sq[i], 32);
    }
    if (q == 0) {
#pragma unroll
        for (int i = 0; i < 2; ++i) {
            int c = (2 * wave + i) * 16 + lr;
            atomicAdd(&sum[c], st[i]);
            atomicAdd(&sumsq[c], sq[i]);
        }
    }
}

__global__ __launch_bounds__(256) void k_gemm1(const int* __restrict__ flag,
        const u16* __restrict__ y0, const u16* __restrict__ agg,
        const void* Wr, const void* Wn,
        const float* __restrict__ sc0, const float* __restrict__ sh0,
        u16* y1_bf /*=d_out*/, u16* y1_ws,
        float* __restrict__ sum, float* __restrict__ sumsq, int n) {
    __shared__ u16 lds[32 * 258];
    u16* y1 = *flag ? y1_bf : y1_ws;
    if (*flag) gemm1_impl<true >(y0, agg, Wr, Wn, sc0, sh0, y1, sum, sumsq, n, lds);
    else       gemm1_impl<false>(y0, agg, Wr, Wn, sc0, sh0, y1, sum, sumsq, n, lds);
}

// ---------------- BN finalize ----------------
__global__ void k_bnfin(const int* __restrict__ flag,
                        const float* __restrict__ sum, const float* __restrict__ sumsq,
                        const void* g, const void* be,
                        float* __restrict__ scale, float* __restrict__ shift, int n) {
    int c = threadIdx.x;
    bool bf = (*flag != 0);
    float inv = 1.f / (float)n;
    float mu = sum[c] * inv;
    float var = fmaxf(sumsq[c] * inv - mu * mu, 0.f);
    float gv = bf ? bf2f(((const u16*)g)[c]) : ((const float*)g)[c];
    float bv = bf ? bf2f(((const u16*)be)[c]) : ((const float*)be)[c];
    float sc = gv * rsqrtf(var + BN_EPS);
    scale[c] = sc;
    shift[c] = bv - mu * sc;
}

// ---------------- final: out = relu(bn1(y1) + x@Wlin^T + blin) ------------
template<bool BF>
__device__ __forceinline__ void final_impl(const void* x, const u16* y1,
                                           const void* Wlin, const void* blin,
                                           const float* sc, const float* sh,
                                           void* out, int n, u16* lds) {
    const int ST = 194;  // 64 x-cols + 128 y1-cols + 2 pad
    int tid = threadIdx.x;
    int wave = tid >> 6, lane = tid & 63, lr = lane & 15, q = lane >> 4;
    long chunk0 = (long)blockIdx.x * 32;

    short8 wf[2][2];
    float blc[2], scc[2], shc[2];
#pragma unroll
    for (int i = 0; i < 2; ++i) {
        int c = (2 * wave + i) * 16 + lr;
#pragma unroll
        for (int ks = 0; ks < 2; ++ks)
            wf[i][ks] = ld8<BF>(Wlin, (long)c * CIN + ks * 32 + q * 8);
        blc[i] = ldf<BF>(blin, c);
        scc[i] = sc[c]; shc[i] = sh[c];
    }
    stage_tile<BF, 64, 32>(x, chunk0, lds, ST, 0, n, tid);
    stage_tile<true, 128, 32>(y1, chunk0, lds, ST, 64, n, tid);
    __syncthreads();

#pragma unroll
    for (int t = 0; t < 2; ++t) {
        short8 a[2];
#pragma unroll
        for (int ks = 0; ks < 2; ++ks)
            a[ks] = *(const short8*)(lds + (t * 16 + lr) * ST + ks * 32 + q * 8);
#pragma unroll
        for (int i = 0; i < 2; ++i) {
            f32x4 acc = {0.f, 0.f, 0.f, 0.f};
            acc = __builtin_amdgcn_mfma_f32_16x16x32_bf16(a[0], wf[i][0], acc, 0, 0, 0);
            acc = __builtin_amdgcn_mfma_f32_16x16x32_bf16(a[1], wf[i][1], acc, 0, 0, 0);
            int c = (2 * wave + i) * 16 + lr;
#pragma unroll
            for (int r = 0; r < 4; ++r) {
                long row = chunk0 + t * 16 + q * 4 + r;
                float yv = bf2f(lds[(t * 16 + q * 4 + r) * ST + 64 + c]);
                float v = acc[r] + blc[i] + yv * scc[i] + shc[i];
                v = fmaxf(v, 0.f);
                if (BF) {
                    pack_store((u16*)out, row, c & ~1, v, n, lane);
                } else if (row < n) {
                    ((float*)out)[row * COUT + c] = v;
                }
            }
        }
    }
}

__global__ __launch_bounds__(256) void k_final(const int* __restrict__ flag,
        const void* x, const void* Wlin, const void* blin,
        const u16* y1_bf /*=d_out*/, const u16* y1_ws,
        const float* __restrict__ sc, const float* __restrict__ sh,
        void* out, int n) {
    __shared__ u16 lds[32 * 194];
    const u16* y1 = *flag ? y1_bf : y1_ws;
    if (*flag) final_impl<true >(x, y1, Wlin, blin, sc, sh, out, n, lds);
    else       final_impl<false>(x, y1, Wlin, blin, sc, sh, out, n, lds);
}

extern "C" void kernel_launch(void* const* d_in, const int* in_sizes, int n_in,
                              void* d_out, int out_size, void* d_ws, size_t ws_size,
                              hipStream_t stream) {
    (void)n_in; (void)out_size; (void)ws_size;
    const void* x    = d_in[0];
    const int*  ei   = (const int*)d_in[1];
    const void* Wr0  = d_in[2];
    const void* Wn0  = d_in[3];
    /* b0 dropped: BN-invariant */
    const void* g0   = d_in[5];
    const void* be0  = d_in[6];
    const void* Wr1  = d_in[7];
    const void* Wn1  = d_in[8];
    /* b1 dropped */
    const void* g1   = d_in[10];
    const void* be1  = d_in[11];
    const void* Wlin = d_in[12];
    const void* blin = d_in[13];

    const int N = in_sizes[0] / CIN;
    const int E = in_sizes[1] / 2;
    const int* src = ei;
    const int* dst = ei + E;
    const int NP = (N + PNODES - 1) >> PSH;   // partitions (<= MAXP for N <= 131072)

    // ---- workspace carve (256B aligned); f32-only region LAST ----
    char* base = (char*)d_ws;
    size_t off = 0;
    auto carve = [&](size_t bytes) -> void* {
        void* p = base + off;
        off = (off + bytes + 255) & ~(size_t)255;
        return p;
    };
    int*   flag      = (int*)carve(256);
    int*   pcount    = (int*)carve(MAXP * sizeof(int));
    int*   pstart    = (int*)carve((MAXP + 1) * sizeof(int));
    int*   pcursor   = (int*)carve(MAXP * CURPAD * sizeof(int));
    float* stats     = (float*)carve(512 * sizeof(float));  // sum0,sq0,sum1,sq1
    float* scsh      = (float*)carve(512 * sizeof(float));  // scale0,shift0,scale1,shift1
    int*   row_start = (int*)carve((size_t)(N + 1) * sizeof(int));
    unsigned int* barr = (unsigned int*)carve((size_t)E * sizeof(int));
    int*   csr       = (int*)carve((size_t)E * sizeof(int));
    u16*   aggu      = (u16*)carve((size_t)N * COUT * sizeof(u16)); // agg0 aliases agg1
    u16*   y0        = (u16*)carve((size_t)N * COUT * sizeof(u16));
    u16*   y1_ws     = (u16*)carve((size_t)N * COUT * sizeof(u16)); // f32 mode only

    hipMemsetAsync(pcount, 0, MAXP * sizeof(int), stream);
    hipMemsetAsync(stats, 0, 512 * sizeof(float), stream);

    const int nwb = (N + 3) / 4;        // wave-per-node blocks
    const int nch = (N + 31) / 32;      // 32-row chunks for dense kernels
    const int ntl = (E + 4095) / 4096;  // pfill tiles

    k_detect<<<1, 64, 0, stream>>>((const unsigned int*)x, flag);

    k_phist<<<256, 256, 0, stream>>>(dst, pcount, E, NP);
    k_pscan<<<1, MAXP, 0, stream>>>(pcount, pstart, pcursor, NP, E);
    k_pfill<<<ntl, 256, 0, stream>>>(src, dst, pcursor, barr, E, NP);
    k_psort<<<NP, 256, 0, stream>>>(barr, pstart, csr, row_start, N, NP, E);

    k_agg0 <<<nwb, 256, 0, stream>>>(flag, x, row_start, csr, aggu, N);
    k_gemm0<<<nch, 256, 0, stream>>>(flag, x, aggu, Wr0, Wn0, y0,
                                     stats, stats + 128, N);
    k_bnfin<<<1, 128, 0, stream>>>(flag, stats, stats + 128, g0, be0,
                                   scsh, scsh + 128, N);

    k_agg1 <<<nwb, 256, 0, stream>>>(y0, row_start, csr, scsh, scsh + 128, aggu, N);
    k_gemm1<<<nch, 256, 0, stream>>>(flag, y0, aggu, Wr1, Wn1, scsh, scsh + 128,
                                     (u16*)d_out, y1_ws, stats + 256, stats + 384, N);
    k_bnfin<<<1, 128, 0, stream>>>(flag, stats + 256, stats + 384, g1, be1,
                                   scsh + 256, scsh + 384, N);

    k_final<<<nch, 256, 0, stream>>>(flag, x, Wlin, blin,
                                     (const u16*)d_out, y1_ws,
                                     scsh + 256, scsh + 384, d_out, N);
}